// Round 15
// baseline (394.411 us; speedup 1.0000x reference)
//
#include <hip/hip_runtime.h>
#include <cstdint>
#include <cstddef>

// ---------- types ----------
typedef __attribute__((ext_vector_type(8))) short short8;        // MFMA bf16 A/B frag (4 VGPR)
typedef __attribute__((ext_vector_type(16))) float f32x16;       // 32x32 MFMA C/D frag
typedef __attribute__((ext_vector_type(4))) unsigned short ushort4_t;

// RNE float->bf16 (finite inputs only)
__device__ __forceinline__ unsigned short f2bf(float f) {
  unsigned u = __float_as_uint(f);
  u += 0x7FFFu + ((u >> 16) & 1u);
  return (unsigned short)(u >> 16);
}

// async global->LDS, 16B per lane. LDS dest is wave-uniform base (+lane*16 implicit).
__device__ __forceinline__ void gload_lds16(const void* g, const void* lds) {
  __builtin_amdgcn_global_load_lds((const __attribute__((address_space(1))) void*)g,
                                   (__attribute__((address_space(3))) void*)lds,
                                   16, 0, 0);
}

// Branch-free erf (A&S 7.1.26, abs err <= 1.5e-7), sign folded via bit ops.
__device__ __forceinline__ float erf_fast(float v) {
  float x = fabsf(v);
  float t = __builtin_amdgcn_rcpf(fmaf(0.3275911f, x, 1.0f));
  float p = fmaf(1.061405429f, t, -1.453152027f);
  p = fmaf(p, t, 1.421413741f);
  p = fmaf(p, t, -0.284496736f);
  p = fmaf(p, t, 0.254829592f);
  p = p * t;
  float e = fmaf(-p, __expf(-x * x), 1.0f);      // erf(|v|), >= 0
  unsigned s = __float_as_uint(v) & 0x80000000u;
  return __uint_as_float(__float_as_uint(e) | s);
}

// ---------- fused quantization kernel (r13, proven) ----------
__device__ __forceinline__ void statsq_row(const float* __restrict__ wr,
                                           unsigned short* __restrict__ wqr, int cols) {
  const int tid = threadIdx.x;
  const float4* w4 = (const float4*)wr;
  const int c4 = cols >> 2;
  float part = 0.f;
  for (int j = tid; j < c4; j += 256) {
    float4 v = w4[j];
    part += fabsf(v.x) + fabsf(v.y) + fabsf(v.z) + fabsf(v.w);
  }
#pragma unroll
  for (int o = 32; o > 0; o >>= 1) part += __shfl_down(part, o, 64);
  __shared__ float wsum[4];
  if ((tid & 63) == 0) wsum[tid >> 6] = part;
  __syncthreads();
  float mean = (wsum[0] + wsum[1] + wsum[2] + wsum[3]) / (float)cols;
  float s = 2.f * mean / sqrtf(127.f);
  ushort4_t* wq4 = (ushort4_t*)wqr;
  for (int j = tid; j < c4; j += 256) {
    float4 v = w4[j];
    float vv[4] = {v.x, v.y, v.z, v.w};
    ushort4_t o;
#pragma unroll
    for (int k = 0; k < 4; ++k) {
      float r = vv[k] / s;
      r = fminf(fmaxf(r, -128.f), 127.f);
      o[k] = f2bf(rintf(r) * s);
    }
    wq4[j] = o;
  }
}

__global__ void quant_fused_kernel(const float* __restrict__ w1, unsigned short* __restrict__ wq1, int C,
                                   const float* __restrict__ w2, unsigned short* __restrict__ wq2, int H,
                                   const float4* __restrict__ x, const float* __restrict__ s_a1,
                                   ushort4_t* __restrict__ xq, int n4, int c4mask) {
  const int NW1 = 4096, NW2 = 1024;
  const int bid = blockIdx.x;
  if (bid < NW1) { statsq_row(w1 + (size_t)bid * C, wq1 + (size_t)bid * C, C); return; }
  if (bid < NW1 + NW2) {
    const int row = bid - NW1;
    statsq_row(w2 + (size_t)row * H, wq2 + (size_t)row * H, H);
    return;
  }
  const int xb = bid - (NW1 + NW2);
  const int nxb = gridDim.x - (NW1 + NW2);
  const int stride = nxb * blockDim.x;
  for (int i = xb * blockDim.x + threadIdx.x; i < n4; i += stride) {
    float4 v = x[i];
    int c = (i & c4mask) << 2;
    float vv[4] = {v.x, v.y, v.z, v.w};
    ushort4_t o;
#pragma unroll
    for (int j = 0; j < 4; ++j) {
      float s = s_a1[c + j];
      float r = vv[j] / s;
      r = fminf(fmaxf(r, -128.f), 127.f);
      o[j] = f2bf(rintf(r) * s);
    }
    xq[i] = o;
  }
}

// ---------- deep-cover 4-phase 256x256 GEMM, 32x32x16 MFMA (A: MxK rm, B: NxK rm) ----------
// r11/r13 schedule verbatim (counts preserved: reads 8/8/4/4 per phase, LGKM 12/4/0,
// VMC(0)+1 BAR per tile). Inner instruction = v_mfma_f32_32x32x16_bf16 (2382 vs
// 2075 TF pipe rate, 4x fewer MFMA issues). Wave tile 128x64 = 4x2 grid of 32x32.
// Operand mapping (analog of m89-verified 16x16x32): lane row = l&31,
// k = (l>>5)*8 + e (8 contiguous bf16 = 1 b128); row&7 == l&7 so the XOR granule
// swizzle property is unchanged. C/D (m74/m101-verified): col = l&31,
// row = (r&3) + 8*(r>>2) + 4*(l>>5), r in [0,16).
#define BAR() { asm volatile("" ::: "memory"); __builtin_amdgcn_s_barrier(); asm volatile("" ::: "memory"); }
#define SB() __builtin_amdgcn_sched_barrier(0)
#define LGKM(n) { asm volatile("s_waitcnt lgkmcnt(" #n ")" ::: "memory"); SB(); }
#define VMC(n) { asm volatile("s_waitcnt vmcnt(" #n ")" ::: "memory"); SB(); }
#define PRIO1() __builtin_amdgcn_s_setprio(1)
#define PRIO0() __builtin_amdgcn_s_setprio(0)

#define RD(p) (*(const short8*)(p))

#define STG(gbase, ldsbuf, h, kt) { \
  _Pragma("unroll") for (int i_ = 0; i_ < 2; ++i_) { \
    const int rb_ = (h) * 128 + (w * 2 + i_) * 8; \
    gload_lds16((gbase) + (size_t)rb_ * K + (size_t)(kt) * 64, (void*)((ldsbuf) + rb_ * 64)); } }

// A-half ah (m-tiles ah*2, ah*2+1): 2 mtiles x 4 ksteps = 8 b128
#define LDA32(dst, buf, ah) { \
  _Pragma("unroll") for (int mi_ = 0; mi_ < 2; ++mi_) { \
    dst[mi_][0] = RD((buf) + aBase + ((ah) * 2 + mi_) * 2048 + ck0); \
    dst[mi_][1] = RD((buf) + aBase + ((ah) * 2 + mi_) * 2048 + ck1); \
    dst[mi_][2] = RD((buf) + aBase + ((ah) * 2 + mi_) * 2048 + ck2); \
    dst[mi_][3] = RD((buf) + aBase + ((ah) * 2 + mi_) * 2048 + ck3); } }

// B n-tile (32 cols): 4 ksteps = 4 b128
#define LDB32(dst, buf, base) { \
  dst[0] = RD((buf) + (base) + ck0); \
  dst[1] = RD((buf) + (base) + ck1); \
  dst[2] = RD((buf) + (base) + ck2); \
  dst[3] = RD((buf) + (base) + ck3); }

// quadrant (a-half ah, b-half nh): 2 mtiles x 4 ksteps = 8 MFMA, acc[4][2] f32x16
#define MMQ32(aH, bH, ah, nh) { \
  _Pragma("unroll") for (int ks_ = 0; ks_ < 4; ++ks_) \
  _Pragma("unroll") for (int mi_ = 0; mi_ < 2; ++mi_) \
    acc[(ah) * 2 + mi_][nh] = __builtin_amdgcn_mfma_f32_32x32x16_bf16( \
        aH[mi_][ks_], bH[ks_], acc[(ah) * 2 + mi_][nh], 0, 0, 0); }

template <int EPI>
__global__ __launch_bounds__(512, 2) void gemm_bt_dc32(
    const unsigned short* __restrict__ A, const unsigned short* __restrict__ B,
    const float* __restrict__ bias, const float* __restrict__ s2,
    const float* __restrict__ beta, unsigned short* __restrict__ Cq,
    float* __restrict__ Cf, int N, int K)
{
  __shared__ __align__(16) unsigned short As0[256 * 64];
  __shared__ __align__(16) unsigned short As1[256 * 64];
  __shared__ __align__(16) unsigned short Bs0[256 * 64];
  __shared__ __align__(16) unsigned short Bs1[256 * 64];

  const int tid = threadIdx.x;
  const int w = tid >> 6, ll = tid & 63;
  const int wr = w >> 2, wc = w & 3;

  // T1: bijective XCD swizzle, y-major slab order (nwg % 8 == 0 for our grids)
  const int nwg = gridDim.x * gridDim.y;
  const int bid = blockIdx.x + gridDim.x * blockIdx.y;
  const int cpx = nwg >> 3;
  const int swz = (bid & 7) * cpx + (bid >> 3);
  const int gy = gridDim.y;
  const int bx = swz / gy, by = swz - bx * gy;   // y fastest within slab
  const long bm = (long)bx * 256;
  const long bn = (long)by * 256;

  // staging source (pre-swizzled so linear LDS dest + XOR read = consistent, rule #21)
  const int srow = ll >> 3;
  const int scol = ((ll & 7) ^ srow) << 3;
  const unsigned short* Agl = A + ((size_t)bm + srow) * K + scol;
  const unsigned short* Bgl = B + ((size_t)bn + srow) * K + scol;

  // per-lane ds_read offsets (u16 elems); 32x32 mapping: row += l&31, khalf = l>>5
  const int l31 = ll & 31, l5 = ll >> 5, l7 = ll & 7;
  const int ck0 = ((0 + l5) ^ l7) * 8;    // kstep 0: granule 0*2 + l5
  const int ck1 = ((2 + l5) ^ l7) * 8;    // kstep 1
  const int ck2 = ((4 + l5) ^ l7) * 8;    // kstep 2
  const int ck3 = ((6 + l5) ^ l7) * 8;    // kstep 3
  const int aBase = (wr * 128 + l31) * 64;
  const int bBase0 = (wc * 32 + l31) * 64;          // b0 strip: staged-half0
  const int bBase1 = (128 + wc * 32 + l31) * 64;    // b1 strip: staged-half1

  f32x16 acc[4][2] = {};
  short8 a0[2][4], a1[2][4], b0[4], b1[4];

  const int nkt = K >> 6;   // 16 (GEMM1) / 64 (GEMM2); >= 4

  // ---- prologue: stage t0 -> buf0, t1 -> buf1; prove t0; pre-read b0(0), a0(0) ----
  STG(Bgl, Bs0, 0, 0); STG(Agl, As0, 0, 0); STG(Agl, As0, 1, 0); STG(Bgl, Bs0, 1, 0);
  STG(Bgl, Bs1, 0, 1); STG(Agl, As1, 0, 1); STG(Agl, As1, 1, 1); STG(Bgl, Bs1, 1, 1);
  VMC(8);                           // t0's 8 drained; t1's 8 in flight
  BAR();
  LDB32(b0, Bs0, bBase0); SB();     // oldest 4
  LDA32(a0, As0, 0); SB();          // next 8  -> 12 outstanding = steady entry

  for (int t = 0; t < nkt; ++t) {
    unsigned short* Asb = (t & 1) ? As1 : As0;
    unsigned short* Bsb = (t & 1) ? Bs1 : Bs0;
    unsigned short* Asn = (t & 1) ? As0 : As1;
    unsigned short* Bsn = (t & 1) ? Bs0 : Bs1;
    const bool i1 = (t + 1 < nkt), i2 = (t + 2 < nkt);

    // p1: issue a1(t), b1(t); drain entry 12 (b0,a0); q00
    LDA32(a1, Asb, 1); SB();
    LDB32(b1, Bsb, bBase1); SB();
    LGKM(12);
    PRIO1(); MMQ32(a0, b0, 0, 0); PRIO0();              // q00

    // p2: drain a1 (b1 stays in flight); q10
    LGKM(4);
    PRIO1(); MMQ32(a1, b0, 1, 0); PRIO0();              // q10

    // p3: drain b1; prove staging; BAR; stage A(t+2)->cur; issue b0(t+1); q01
    LGKM(0); VMC(0); BAR();
    if (i2) { STG(Agl, Asb, 0, t + 2); STG(Agl, Asb, 1, t + 2); }
    if (i1) { LDB32(b0, Bsn, bBase0); SB(); }
    PRIO1(); MMQ32(a0, b1, 0, 1); PRIO0();              // q01

    // p4: stage B(t+2)->cur; issue a0(t+1); q11 (no wait)
    if (i2) { STG(Bgl, Bsb, 0, t + 2); STG(Bgl, Bsb, 1, t + 2); }
    if (i1) { LDA32(a0, Asn, 0); SB(); }
    PRIO1(); MMQ32(a1, b1, 1, 1); PRIO0();              // q11
  }

  // ---- epilogue; 32x32 C/D layout: col = l&31, row = (r&3)+8*(r>>2)+4*(l>>5) ----
  // NT 0 -> cols bn + wc*32 ; NT 1 -> cols bn + 128 + wc*32
#pragma unroll
  for (int NT = 0; NT < 2; ++NT) {
    const long col = bn + wc * 32 + NT * 128 + l31;
    const float bv = bias[col];
    float sv = 1.f, bev = 0.f, inv = 1.f;
    if (EPI == 0) { sv = s2[col]; bev = beta[col]; inv = 1.0f / sv; }
#pragma unroll
    for (int MT = 0; MT < 4; ++MT) {
#pragma unroll
      for (int r = 0; r < 16; ++r) {
        const size_t rowg = (size_t)(bm + wr * 128 + MT * 32 +
                                     (r & 3) + 8 * (r >> 2) + 4 * l5);
        float v = acc[MT][NT][r] + bv;
        if (EPI == 0) {
          float g = 0.5f * v * (1.f + erf_fast(v * 0.70710678118654752f));
          float rr = (g - bev) * inv;
          rr = fminf(fmaxf(rr, 0.f), 255.f);
          Cq[rowg * N + col] = f2bf(fmaf(rintf(rr), sv, bev));
        } else {
          Cf[rowg * N + col] = v;
        }
      }
    }
  }
}

// ---------- launch ----------
extern "C" void kernel_launch(void* const* d_in, const int* in_sizes, int n_in,
                              void* d_out, int out_size, void* d_ws, size_t ws_size,
                              hipStream_t stream) {
  const float* x     = (const float*)d_in[0];
  const float* w1    = (const float*)d_in[1];
  const float* b1    = (const float*)d_in[2];
  const float* w2    = (const float*)d_in[3];
  const float* b2    = (const float*)d_in[4];
  const float* s_a1  = (const float*)d_in[5];
  const float* s_a2  = (const float*)d_in[6];
  const float* beta2 = (const float*)d_in[7];
  float* out = (float*)d_out;

  const int C = 1024, H = 4096;
  const int M = in_sizes[0] / C;  // 16384

  // workspace layout (bf16 bit-patterns as u16): xq | wq1 | wq2 | hq
  unsigned short* xq  = (unsigned short*)d_ws;
  unsigned short* wq1 = xq  + (size_t)M * C;
  unsigned short* wq2 = wq1 + (size_t)H * C;
  unsigned short* hq  = wq2 + (size_t)C * H;

  quant_fused_kernel<<<4096 + 1024 + 2048, 256, 0, stream>>>(
      w1, wq1, C, w2, wq2, H,
      (const float4*)x, s_a1, (ushort4_t*)xq, M * C / 4, C / 4 - 1);

  dim3 g1(M / 256, H / 256);  // 64 x 16
  gemm_bt_dc32<0><<<g1, 512, 0, stream>>>(xq, wq1, b1, s_a2, beta2, hq, nullptr, H, C);
  dim3 g2(M / 256, C / 256);  // 64 x 4
  gemm_bt_dc32<1><<<g2, 512, 0, stream>>>(hq, wq2, b2, nullptr, nullptr, nullptr, out, C, H);
}

// Round 16
// 318.510 us; speedup vs baseline: 1.2383x; 1.2383x over previous
//
#include <hip/hip_runtime.h>
#include <cstdint>
#include <cstddef>

// ---------- types ----------
typedef __attribute__((ext_vector_type(8))) short short8;        // MFMA bf16 A/B frag (4 VGPR)
typedef __attribute__((ext_vector_type(4))) float f32x4;         // MFMA C/D frag
typedef __attribute__((ext_vector_type(4))) unsigned short ushort4_t;

// RNE float->bf16 (finite inputs only)
__device__ __forceinline__ unsigned short f2bf(float f) {
  unsigned u = __float_as_uint(f);
  u += 0x7FFFu + ((u >> 16) & 1u);
  return (unsigned short)(u >> 16);
}

// async global->LDS, 16B per lane. LDS dest is wave-uniform base (+lane*16 implicit).
__device__ __forceinline__ void gload_lds16(const void* g, const void* lds) {
  __builtin_amdgcn_global_load_lds((const __attribute__((address_space(1))) void*)g,
                                   (__attribute__((address_space(3))) void*)lds,
                                   16, 0, 0);
}

// Branch-free erf (A&S 7.1.26, abs err <= 1.5e-7), sign folded via bit ops.
__device__ __forceinline__ float erf_fast(float v) {
  float x = fabsf(v);
  float t = __builtin_amdgcn_rcpf(fmaf(0.3275911f, x, 1.0f));
  float p = fmaf(1.061405429f, t, -1.453152027f);
  p = fmaf(p, t, 1.421413741f);
  p = fmaf(p, t, -0.284496736f);
  p = fmaf(p, t, 0.254829592f);
  p = p * t;
  float e = fmaf(-p, __expf(-x * x), 1.0f);      // erf(|v|), >= 0
  unsigned s = __float_as_uint(v) & 0x80000000u;
  return __uint_as_float(__float_as_uint(e) | s);
}

// ---------- fused quantization kernel (r13, proven) ----------
__device__ __forceinline__ void statsq_row(const float* __restrict__ wr,
                                           unsigned short* __restrict__ wqr, int cols) {
  const int tid = threadIdx.x;
  const float4* w4 = (const float4*)wr;
  const int c4 = cols >> 2;
  float part = 0.f;
  for (int j = tid; j < c4; j += 256) {
    float4 v = w4[j];
    part += fabsf(v.x) + fabsf(v.y) + fabsf(v.z) + fabsf(v.w);
  }
#pragma unroll
  for (int o = 32; o > 0; o >>= 1) part += __shfl_down(part, o, 64);
  __shared__ float wsum[4];
  if ((tid & 63) == 0) wsum[tid >> 6] = part;
  __syncthreads();
  float mean = (wsum[0] + wsum[1] + wsum[2] + wsum[3]) / (float)cols;
  float s = 2.f * mean / sqrtf(127.f);
  ushort4_t* wq4 = (ushort4_t*)wqr;
  for (int j = tid; j < c4; j += 256) {
    float4 v = w4[j];
    float vv[4] = {v.x, v.y, v.z, v.w};
    ushort4_t o;
#pragma unroll
    for (int k = 0; k < 4; ++k) {
      float r = vv[k] / s;
      r = fminf(fmaxf(r, -128.f), 127.f);
      o[k] = f2bf(rintf(r) * s);
    }
    wq4[j] = o;
  }
}

__global__ void quant_fused_kernel(const float* __restrict__ w1, unsigned short* __restrict__ wq1, int C,
                                   const float* __restrict__ w2, unsigned short* __restrict__ wq2, int H,
                                   const float4* __restrict__ x, const float* __restrict__ s_a1,
                                   ushort4_t* __restrict__ xq, int n4, int c4mask) {
  const int NW1 = 4096, NW2 = 1024;
  const int bid = blockIdx.x;
  if (bid < NW1) { statsq_row(w1 + (size_t)bid * C, wq1 + (size_t)bid * C, C); return; }
  if (bid < NW1 + NW2) {
    const int row = bid - NW1;
    statsq_row(w2 + (size_t)row * H, wq2 + (size_t)row * H, H);
    return;
  }
  const int xb = bid - (NW1 + NW2);
  const int nxb = gridDim.x - (NW1 + NW2);
  const int stride = nxb * blockDim.x;
  for (int i = xb * blockDim.x + threadIdx.x; i < n4; i += stride) {
    float4 v = x[i];
    int c = (i & c4mask) << 2;
    float vv[4] = {v.x, v.y, v.z, v.w};
    ushort4_t o;
#pragma unroll
    for (int j = 0; j < 4; ++j) {
      float s = s_a1[c + j];
      float r = vv[j] / s;
      r = fminf(fmaxf(r, -128.f), 127.f);
      o[j] = f2bf(rintf(r) * s);
    }
    xq[i] = o;
  }
}

// ---------- deep-cover 4-phase 256x256 GEMM (A: MxK rm, B: NxK rm) ----------
// r13 (best measured) + a1-read migration: a1(t) is read at END of p4(t-1), after
// q11's last use of the a1 registers, instead of at p1(t). Entry outstanding = 20
// (b0,a0,a1 in FIFO order); p1 issues only b1.
//   p1: issue b1(t) [24]; LGKM(12) [drain b0,a0; keep a1+b1]; q00=a0*b0
//   p2: LGKM(4) [drain a1; keep b1];                          q10=a1*b0
//   p3: LGKM(0); VMC(0); BAR; STG A(t+2)->cur; read b0(t+1);  q01=a0*b1
//   p4: STG B(t+2)->cur; read a0(t+1); q11=a1*b1; read a1(t+1)
// Cover: a1 waited@p2, issued p4-prev (q11+p1 = ~400cy); b1 waited@p3 (q00+q10).
// WAR/stage audit (= r13): all cur-buf reads drained per-wave by p3's LGKM(0)
// (b0,a0 @LGKM(12); a1 @LGKM(4); b1 @LGKM(0)); BAR; STG(t+2)->cur post-BAR safe.
// Next-buf reads (b0@p3, a0@p4, a1@p4-end) all post-VMC(0)+BAR proof of their
// staging (issued >=1 full tile earlier). VMC(0) unconditional -> no tail races.
// Register WAR: a1-read placed after q11 (its last consumer) in program order.
#define BAR() { asm volatile("" ::: "memory"); __builtin_amdgcn_s_barrier(); asm volatile("" ::: "memory"); }
#define SB() __builtin_amdgcn_sched_barrier(0)
#define LGKM(n) { asm volatile("s_waitcnt lgkmcnt(" #n ")" ::: "memory"); SB(); }
#define VMC(n) { asm volatile("s_waitcnt vmcnt(" #n ")" ::: "memory"); SB(); }
#define PRIO1() __builtin_amdgcn_s_setprio(1)
#define PRIO0() __builtin_amdgcn_s_setprio(0)

#define STG(gbase, ldsbuf, h, kt) { \
  _Pragma("unroll") for (int i_ = 0; i_ < 2; ++i_) { \
    const int rb_ = (h) * 128 + (w * 2 + i_) * 8; \
    gload_lds16((gbase) + (size_t)rb_ * K + (size_t)(kt) * 64, (void*)((ldsbuf) + rb_ * 64)); } }

#define LDA_(dst, buf, mh) { \
  _Pragma("unroll") for (int mi_ = 0; mi_ < 4; ++mi_) { \
    dst[mi_][0] = *(const short8*)((buf) + aBase + (mh) * 4096 + mi_ * 1024 + ck0); \
    dst[mi_][1] = *(const short8*)((buf) + aBase + (mh) * 4096 + mi_ * 1024 + ck1); } }

#define LDBX(dst, buf, base) { \
  _Pragma("unroll") for (int ni_ = 0; ni_ < 2; ++ni_) { \
    dst[ni_][0] = *(const short8*)((buf) + (base) + ni_ * 1024 + ck0); \
    dst[ni_][1] = *(const short8*)((buf) + (base) + ni_ * 1024 + ck1); } }

#define MMQ(aR, bR, mh, nh) { \
  _Pragma("unroll") for (int kk_ = 0; kk_ < 2; ++kk_) \
  _Pragma("unroll") for (int mi_ = 0; mi_ < 4; ++mi_) \
  _Pragma("unroll") for (int ni_ = 0; ni_ < 2; ++ni_) \
    acc[(mh) * 4 + mi_][(nh) * 2 + ni_] = __builtin_amdgcn_mfma_f32_16x16x32_bf16( \
        aR[mi_][kk_], bR[ni_][kk_], acc[(mh) * 4 + mi_][(nh) * 2 + ni_], 0, 0, 0); }

template <int EPI>
__global__ __launch_bounds__(512, 2) void gemm_bt_dc(
    const unsigned short* __restrict__ A, const unsigned short* __restrict__ B,
    const float* __restrict__ bias, const float* __restrict__ s2,
    const float* __restrict__ beta, unsigned short* __restrict__ Cq,
    float* __restrict__ Cf, int N, int K)
{
  __shared__ __align__(16) unsigned short As0[256 * 64];
  __shared__ __align__(16) unsigned short As1[256 * 64];
  __shared__ __align__(16) unsigned short Bs0[256 * 64];
  __shared__ __align__(16) unsigned short Bs1[256 * 64];

  const int tid = threadIdx.x;
  const int w = tid >> 6, ll = tid & 63;
  const int wr = w >> 2, wc = w & 3;

  // T1: bijective XCD swizzle, y-major slab order (nwg % 8 == 0 for our grids)
  const int nwg = gridDim.x * gridDim.y;
  const int bid = blockIdx.x + gridDim.x * blockIdx.y;
  const int cpx = nwg >> 3;
  const int swz = (bid & 7) * cpx + (bid >> 3);
  const int gy = gridDim.y;
  const int bx = swz / gy, by = swz - bx * gy;   // y fastest within slab
  const long bm = (long)bx * 256;
  const long bn = (long)by * 256;

  // staging source (pre-swizzled so linear LDS dest + XOR read = consistent, rule #21)
  const int srow = ll >> 3;
  const int scol = ((ll & 7) ^ srow) << 3;
  const unsigned short* Agl = A + ((size_t)bm + srow) * K + scol;
  const unsigned short* Bgl = B + ((size_t)bn + srow) * K + scol;

  // per-lane ds_read offsets (u16 elems)
  const int lhi = ll >> 4, llo = ll & 15, l7 = ll & 7;
  const int ck0 = ((0 * 4 + lhi) ^ l7) * 8;
  const int ck1 = ((1 * 4 + lhi) ^ l7) * 8;
  const int aBase = (wr * 128 + llo) * 64;
  const int bBase0 = (wc * 32 + llo) * 64;          // b0 strip: staged-half0
  const int bBase1 = (128 + wc * 32 + llo) * 64;    // b1 strip: staged-half1

  f32x4 acc[8][4] = {};
  short8 a0[4][2], a1[4][2], b0[2][2], b1[2][2];

  const int nkt = K >> 6;   // 16 (GEMM1) / 64 (GEMM2); >= 4

  // ---- prologue: stage t0 -> buf0, t1 -> buf1; prove t0; pre-read b0,a0,a1 (0) ----
  STG(Bgl, Bs0, 0, 0); STG(Agl, As0, 0, 0); STG(Agl, As0, 1, 0); STG(Bgl, Bs0, 1, 0);
  STG(Bgl, Bs1, 0, 1); STG(Agl, As1, 0, 1); STG(Agl, As1, 1, 1); STG(Bgl, Bs1, 1, 1);
  VMC(8);                           // t0's 8 drained; t1's 8 in flight
  BAR();
  LDBX(b0, Bs0, bBase0); SB();      // oldest 4
  LDA_(a0, As0, 0); SB();           // next 8
  LDA_(a1, As0, 1); SB();           // next 8  -> 20 outstanding = steady entry

  for (int t = 0; t < nkt; ++t) {
    unsigned short* Asb = (t & 1) ? As1 : As0;
    unsigned short* Bsb = (t & 1) ? Bs1 : Bs0;
    unsigned short* Asn = (t & 1) ? As0 : As1;
    unsigned short* Bsn = (t & 1) ? Bs0 : Bs1;
    const bool i1 = (t + 1 < nkt), i2 = (t + 2 < nkt);

    // p1: issue b1(t); drain b0,a0 (keep a1+b1 = 12); q00
    LDBX(b1, Bsb, bBase1); SB();
    LGKM(12);
    PRIO1(); MMQ(a0, b0, 0, 0); PRIO0();                // q00

    // p2: drain a1 (b1 stays in flight); q10
    LGKM(4);
    PRIO1(); MMQ(a1, b0, 1, 0); PRIO0();                // q10

    // p3: drain b1; prove staging; BAR; stage A(t+2)->cur; read b0(t+1); q01
    LGKM(0); VMC(0); BAR();
    if (i2) { STG(Agl, Asb, 0, t + 2); STG(Agl, Asb, 1, t + 2); }
    if (i1) { LDBX(b0, Bsn, bBase0); SB(); }
    PRIO1(); MMQ(a0, b1, 0, 1); PRIO0();                // q01

    // p4: stage B(t+2)->cur; read a0(t+1); q11; read a1(t+1) (after q11's last use)
    if (i2) { STG(Bgl, Bsb, 0, t + 2); STG(Bgl, Bsb, 1, t + 2); }
    if (i1) { LDA_(a0, Asn, 0); SB(); }
    PRIO1(); MMQ(a1, b1, 1, 1); PRIO0();                // q11
    if (i1) { LDA_(a1, Asn, 1); SB(); }
  }

  // ---- epilogue; C/D layout: col = lane&15, row = (lane>>4)*4 + reg ----
  // NI 0,1 -> cols bn + wc*32 + NI*16 ; NI 2,3 -> cols bn + 128 + wc*32 + (NI-2)*16
  const int lr = lhi;
  const int lc = llo;
#pragma unroll
  for (int NI = 0; NI < 4; ++NI) {
    const long col = bn + wc * 32 + ((NI >= 2) ? 128 : 0) + (NI & 1) * 16 + lc;
    const float bv = bias[col];
    float sv = 1.f, bev = 0.f, inv = 1.f;
    if (EPI == 0) { sv = s2[col]; bev = beta[col]; inv = 1.0f / sv; }
#pragma unroll
    for (int MI = 0; MI < 8; ++MI) {
#pragma unroll
      for (int r = 0; r < 4; ++r) {
        const size_t rowg = (size_t)(bm + wr * 128 + MI * 16 + lr * 4 + r);
        float v = acc[MI][NI][r] + bv;
        if (EPI == 0) {
          float g = 0.5f * v * (1.f + erf_fast(v * 0.70710678118654752f));
          float rr = (g - bev) * inv;
          rr = fminf(fmaxf(rr, 0.f), 255.f);
          Cq[rowg * N + col] = f2bf(fmaf(rintf(rr), sv, bev));
        } else {
          Cf[rowg * N + col] = v;
        }
      }
    }
  }
}

// ---------- launch ----------
extern "C" void kernel_launch(void* const* d_in, const int* in_sizes, int n_in,
                              void* d_out, int out_size, void* d_ws, size_t ws_size,
                              hipStream_t stream) {
  const float* x     = (const float*)d_in[0];
  const float* w1    = (const float*)d_in[1];
  const float* b1    = (const float*)d_in[2];
  const float* w2    = (const float*)d_in[3];
  const float* b2    = (const float*)d_in[4];
  const float* s_a1  = (const float*)d_in[5];
  const float* s_a2  = (const float*)d_in[6];
  const float* beta2 = (const float*)d_in[7];
  float* out = (float*)d_out;

  const int C = 1024, H = 4096;
  const int M = in_sizes[0] / C;  // 16384

  // workspace layout (bf16 bit-patterns as u16): xq | wq1 | wq2 | hq
  unsigned short* xq  = (unsigned short*)d_ws;
  unsigned short* wq1 = xq  + (size_t)M * C;
  unsigned short* wq2 = wq1 + (size_t)H * C;
  unsigned short* hq  = wq2 + (size_t)C * H;

  quant_fused_kernel<<<4096 + 1024 + 2048, 256, 0, stream>>>(
      w1, wq1, C, w2, wq2, H,
      (const float4*)x, s_a1, (ushort4_t*)xq, M * C / 4, C / 4 - 1);

  dim3 g1(M / 256, H / 256);  // 64 x 16
  gemm_bt_dc<0><<<g1, 512, 0, stream>>>(xq, wq1, b1, s_a2, beta2, hq, nullptr, H, C);
  dim3 g2(M / 256, C / 256);  // 64 x 4
  gemm_bt_dc<1><<<g2, 512, 0, stream>>>(hq, wq2, b2, nullptr, nullptr, nullptr, out, C, H);
}

// Round 17
// 312.853 us; speedup vs baseline: 1.2607x; 1.0181x over previous
//
#include <hip/hip_runtime.h>
#include <cstdint>
#include <cstddef>

// ---------- types ----------
typedef __attribute__((ext_vector_type(8))) short short8;        // MFMA bf16 A/B frag (4 VGPR)
typedef __attribute__((ext_vector_type(4))) float f32x4;         // MFMA C/D frag
typedef __attribute__((ext_vector_type(4))) unsigned short ushort4_t;

// RNE float->bf16 (finite inputs only)
__device__ __forceinline__ unsigned short f2bf(float f) {
  unsigned u = __float_as_uint(f);
  u += 0x7FFFu + ((u >> 16) & 1u);
  return (unsigned short)(u >> 16);
}

// async global->LDS, 16B per lane. LDS dest is wave-uniform base (+lane*16 implicit).
__device__ __forceinline__ void gload_lds16(const void* g, const void* lds) {
  __builtin_amdgcn_global_load_lds((const __attribute__((address_space(1))) void*)g,
                                   (__attribute__((address_space(3))) void*)lds,
                                   16, 0, 0);
}

// Branch-free erf (A&S 7.1.26, abs err <= 1.5e-7), sign folded via bit ops.
__device__ __forceinline__ float erf_fast(float v) {
  float x = fabsf(v);
  float t = __builtin_amdgcn_rcpf(fmaf(0.3275911f, x, 1.0f));
  float p = fmaf(1.061405429f, t, -1.453152027f);
  p = fmaf(p, t, 1.421413741f);
  p = fmaf(p, t, -0.284496736f);
  p = fmaf(p, t, 0.254829592f);
  p = p * t;
  float e = fmaf(-p, __expf(-x * x), 1.0f);      // erf(|v|), >= 0
  unsigned s = __float_as_uint(v) & 0x80000000u;
  return __uint_as_float(__float_as_uint(e) | s);
}

// ---------- fused quantization kernel (load-balanced r17) ----------
// bid-space, heaviest-first: w2-rows [0,1024) (~40KB/blk), x-quant [1024,9216)
// (~12KB/blk, 8192 blocks), w1-rows [9216,13312) (~10KB/blk). Math identical to r13.
__device__ __forceinline__ void statsq_row(const float* __restrict__ wr,
                                           unsigned short* __restrict__ wqr, int cols) {
  const int tid = threadIdx.x;
  const float4* w4 = (const float4*)wr;
  const int c4 = cols >> 2;
  float part = 0.f;
  for (int j = tid; j < c4; j += 256) {
    float4 v = w4[j];
    part += fabsf(v.x) + fabsf(v.y) + fabsf(v.z) + fabsf(v.w);
  }
#pragma unroll
  for (int o = 32; o > 0; o >>= 1) part += __shfl_down(part, o, 64);
  __shared__ float wsum[4];
  if ((tid & 63) == 0) wsum[tid >> 6] = part;
  __syncthreads();
  float mean = (wsum[0] + wsum[1] + wsum[2] + wsum[3]) / (float)cols;
  float s = 2.f * mean / sqrtf(127.f);
  ushort4_t* wq4 = (ushort4_t*)wqr;
  for (int j = tid; j < c4; j += 256) {
    float4 v = w4[j];
    float vv[4] = {v.x, v.y, v.z, v.w};
    ushort4_t o;
#pragma unroll
    for (int k = 0; k < 4; ++k) {
      float r = vv[k] / s;
      r = fminf(fmaxf(r, -128.f), 127.f);
      o[k] = f2bf(rintf(r) * s);
    }
    wq4[j] = o;
  }
}

__global__ void quant_fused_kernel(const float* __restrict__ w1, unsigned short* __restrict__ wq1, int C,
                                   const float* __restrict__ w2, unsigned short* __restrict__ wq2, int H,
                                   const float4* __restrict__ x, const float* __restrict__ s_a1,
                                   ushort4_t* __restrict__ xq, int n4, int c4mask) {
  const int NW2 = 1024, NXB = 8192, NW1 = 4096;
  const int bid = blockIdx.x;
  if (bid < NW2) {                                   // w2 rows (heaviest) first
    statsq_row(w2 + (size_t)bid * H, wq2 + (size_t)bid * H, H);
    return;
  }
  if (bid < NW2 + NXB) {                             // x quant: grid-stride float4
    const int xb = bid - NW2;
    const int stride = NXB * blockDim.x;
    for (int i = xb * blockDim.x + threadIdx.x; i < n4; i += stride) {
      float4 v = x[i];
      int c = (i & c4mask) << 2;                     // channel base (C is pow2)
      float vv[4] = {v.x, v.y, v.z, v.w};
      ushort4_t o;
#pragma unroll
      for (int j = 0; j < 4; ++j) {
        float s = s_a1[c + j];
        float r = vv[j] / s;
        r = fminf(fmaxf(r, -128.f), 127.f);
        o[j] = f2bf(rintf(r) * s);
      }
      xq[i] = o;
    }
    return;
  }
  const int row = bid - (NW2 + NXB);                 // w1 rows
  if (row < NW1) statsq_row(w1 + (size_t)row * C, wq1 + (size_t)row * C, C);
}

// ---------- deep-cover 4-phase 256x256 GEMM (A: MxK rm, B: NxK rm) ----------
// r16 verbatim (best measured; GEMM1 844 TF / GEMM2 ~947 TF = this structure's
// ceiling after 7 schedule variants). a1(t+1) read at end of p4(t) (post-q11 WAR
// window); entry outstanding = 20 (b0,a0,a1 FIFO); counted LGKM 12/4/0; VMC(0)+
// single BAR per tile (stage->read and WAR proof chains audited, no tail races).
#define BAR() { asm volatile("" ::: "memory"); __builtin_amdgcn_s_barrier(); asm volatile("" ::: "memory"); }
#define SB() __builtin_amdgcn_sched_barrier(0)
#define LGKM(n) { asm volatile("s_waitcnt lgkmcnt(" #n ")" ::: "memory"); SB(); }
#define VMC(n) { asm volatile("s_waitcnt vmcnt(" #n ")" ::: "memory"); SB(); }
#define PRIO1() __builtin_amdgcn_s_setprio(1)
#define PRIO0() __builtin_amdgcn_s_setprio(0)

#define STG(gbase, ldsbuf, h, kt) { \
  _Pragma("unroll") for (int i_ = 0; i_ < 2; ++i_) { \
    const int rb_ = (h) * 128 + (w * 2 + i_) * 8; \
    gload_lds16((gbase) + (size_t)rb_ * K + (size_t)(kt) * 64, (void*)((ldsbuf) + rb_ * 64)); } }

#define LDA_(dst, buf, mh) { \
  _Pragma("unroll") for (int mi_ = 0; mi_ < 4; ++mi_) { \
    dst[mi_][0] = *(const short8*)((buf) + aBase + (mh) * 4096 + mi_ * 1024 + ck0); \
    dst[mi_][1] = *(const short8*)((buf) + aBase + (mh) * 4096 + mi_ * 1024 + ck1); } }

#define LDBX(dst, buf, base) { \
  _Pragma("unroll") for (int ni_ = 0; ni_ < 2; ++ni_) { \
    dst[ni_][0] = *(const short8*)((buf) + (base) + ni_ * 1024 + ck0); \
    dst[ni_][1] = *(const short8*)((buf) + (base) + ni_ * 1024 + ck1); } }

#define MMQ(aR, bR, mh, nh) { \
  _Pragma("unroll") for (int kk_ = 0; kk_ < 2; ++kk_) \
  _Pragma("unroll") for (int mi_ = 0; mi_ < 4; ++mi_) \
  _Pragma("unroll") for (int ni_ = 0; ni_ < 2; ++ni_) \
    acc[(mh) * 4 + mi_][(nh) * 2 + ni_] = __builtin_amdgcn_mfma_f32_16x16x32_bf16( \
        aR[mi_][kk_], bR[ni_][kk_], acc[(mh) * 4 + mi_][(nh) * 2 + ni_], 0, 0, 0); }

template <int EPI>
__global__ __launch_bounds__(512, 2) void gemm_bt_dc(
    const unsigned short* __restrict__ A, const unsigned short* __restrict__ B,
    const float* __restrict__ bias, const float* __restrict__ s2,
    const float* __restrict__ beta, unsigned short* __restrict__ Cq,
    float* __restrict__ Cf, int N, int K)
{
  __shared__ __align__(16) unsigned short As0[256 * 64];
  __shared__ __align__(16) unsigned short As1[256 * 64];
  __shared__ __align__(16) unsigned short Bs0[256 * 64];
  __shared__ __align__(16) unsigned short Bs1[256 * 64];

  const int tid = threadIdx.x;
  const int w = tid >> 6, ll = tid & 63;
  const int wr = w >> 2, wc = w & 3;

  // T1: bijective XCD swizzle, y-major slab order (nwg % 8 == 0 for our grids)
  const int nwg = gridDim.x * gridDim.y;
  const int bid = blockIdx.x + gridDim.x * blockIdx.y;
  const int cpx = nwg >> 3;
  const int swz = (bid & 7) * cpx + (bid >> 3);
  const int gy = gridDim.y;
  const int bx = swz / gy, by = swz - bx * gy;   // y fastest within slab
  const long bm = (long)bx * 256;
  const long bn = (long)by * 256;

  // staging source (pre-swizzled so linear LDS dest + XOR read = consistent, rule #21)
  const int srow = ll >> 3;
  const int scol = ((ll & 7) ^ srow) << 3;
  const unsigned short* Agl = A + ((size_t)bm + srow) * K + scol;
  const unsigned short* Bgl = B + ((size_t)bn + srow) * K + scol;

  // per-lane ds_read offsets (u16 elems)
  const int lhi = ll >> 4, llo = ll & 15, l7 = ll & 7;
  const int ck0 = ((0 * 4 + lhi) ^ l7) * 8;
  const int ck1 = ((1 * 4 + lhi) ^ l7) * 8;
  const int aBase = (wr * 128 + llo) * 64;
  const int bBase0 = (wc * 32 + llo) * 64;          // b0 strip: staged-half0
  const int bBase1 = (128 + wc * 32 + llo) * 64;    // b1 strip: staged-half1

  f32x4 acc[8][4] = {};
  short8 a0[4][2], a1[4][2], b0[2][2], b1[2][2];

  const int nkt = K >> 6;   // 16 (GEMM1) / 64 (GEMM2); >= 4

  // ---- prologue: stage t0 -> buf0, t1 -> buf1; prove t0; pre-read b0,a0,a1 (0) ----
  STG(Bgl, Bs0, 0, 0); STG(Agl, As0, 0, 0); STG(Agl, As0, 1, 0); STG(Bgl, Bs0, 1, 0);
  STG(Bgl, Bs1, 0, 1); STG(Agl, As1, 0, 1); STG(Agl, As1, 1, 1); STG(Bgl, Bs1, 1, 1);
  VMC(8);                           // t0's 8 drained; t1's 8 in flight
  BAR();
  LDBX(b0, Bs0, bBase0); SB();      // oldest 4
  LDA_(a0, As0, 0); SB();           // next 8
  LDA_(a1, As0, 1); SB();           // next 8  -> 20 outstanding = steady entry

  for (int t = 0; t < nkt; ++t) {
    unsigned short* Asb = (t & 1) ? As1 : As0;
    unsigned short* Bsb = (t & 1) ? Bs1 : Bs0;
    unsigned short* Asn = (t & 1) ? As0 : As1;
    unsigned short* Bsn = (t & 1) ? Bs0 : Bs1;
    const bool i1 = (t + 1 < nkt), i2 = (t + 2 < nkt);

    // p1: issue b1(t); drain b0,a0 (keep a1+b1 = 12); q00
    LDBX(b1, Bsb, bBase1); SB();
    LGKM(12);
    PRIO1(); MMQ(a0, b0, 0, 0); PRIO0();                // q00

    // p2: drain a1 (b1 stays in flight); q10
    LGKM(4);
    PRIO1(); MMQ(a1, b0, 1, 0); PRIO0();                // q10

    // p3: drain b1; prove staging; BAR; stage A(t+2)->cur; read b0(t+1); q01
    LGKM(0); VMC(0); BAR();
    if (i2) { STG(Agl, Asb, 0, t + 2); STG(Agl, Asb, 1, t + 2); }
    if (i1) { LDBX(b0, Bsn, bBase0); SB(); }
    PRIO1(); MMQ(a0, b1, 0, 1); PRIO0();                // q01

    // p4: stage B(t+2)->cur; read a0(t+1); q11; read a1(t+1) (after q11's last use)
    if (i2) { STG(Bgl, Bsb, 0, t + 2); STG(Bgl, Bsb, 1, t + 2); }
    if (i1) { LDA_(a0, Asn, 0); SB(); }
    PRIO1(); MMQ(a1, b1, 1, 1); PRIO0();                // q11
    if (i1) { LDA_(a1, Asn, 1); SB(); }
  }

  // ---- epilogue; C/D layout: col = lane&15, row = (lane>>4)*4 + reg ----
  // NI 0,1 -> cols bn + wc*32 + NI*16 ; NI 2,3 -> cols bn + 128 + wc*32 + (NI-2)*16
  const int lr = lhi;
  const int lc = llo;
#pragma unroll
  for (int NI = 0; NI < 4; ++NI) {
    const long col = bn + wc * 32 + ((NI >= 2) ? 128 : 0) + (NI & 1) * 16 + lc;
    const float bv = bias[col];
    float sv = 1.f, bev = 0.f, inv = 1.f;
    if (EPI == 0) { sv = s2[col]; bev = beta[col]; inv = 1.0f / sv; }
#pragma unroll
    for (int MI = 0; MI < 8; ++MI) {
#pragma unroll
      for (int r = 0; r < 4; ++r) {
        const size_t rowg = (size_t)(bm + wr * 128 + MI * 16 + lr * 4 + r);
        float v = acc[MI][NI][r] + bv;
        if (EPI == 0) {
          float g = 0.5f * v * (1.f + erf_fast(v * 0.70710678118654752f));
          float rr = (g - bev) * inv;
          rr = fminf(fmaxf(rr, 0.f), 255.f);
          Cq[rowg * N + col] = f2bf(fmaf(rintf(rr), sv, bev));
        } else {
          Cf[rowg * N + col] = v;
        }
      }
    }
  }
}

// ---------- launch ----------
extern "C" void kernel_launch(void* const* d_in, const int* in_sizes, int n_in,
                              void* d_out, int out_size, void* d_ws, size_t ws_size,
                              hipStream_t stream) {
  const float* x     = (const float*)d_in[0];
  const float* w1    = (const float*)d_in[1];
  const float* b1    = (const float*)d_in[2];
  const float* w2    = (const float*)d_in[3];
  const float* b2    = (const float*)d_in[4];
  const float* s_a1  = (const float*)d_in[5];
  const float* s_a2  = (const float*)d_in[6];
  const float* beta2 = (const float*)d_in[7];
  float* out = (float*)d_out;

  const int C = 1024, H = 4096;
  const int M = in_sizes[0] / C;  // 16384

  // workspace layout (bf16 bit-patterns as u16): xq | wq1 | wq2 | hq
  unsigned short* xq  = (unsigned short*)d_ws;
  unsigned short* wq1 = xq  + (size_t)M * C;
  unsigned short* wq2 = wq1 + (size_t)H * C;
  unsigned short* hq  = wq2 + (size_t)C * H;

  // fused quant, load-balanced: 1024 w2-rows + 8192 x-blocks + 4096 w1-rows
  quant_fused_kernel<<<1024 + 8192 + 4096, 256, 0, stream>>>(
      w1, wq1, C, w2, wq2, H,
      (const float4*)x, s_a1, (ushort4_t*)xq, M * C / 4, C / 4 - 1);

  dim3 g1(M / 256, H / 256);  // 64 x 16
  gemm_bt_dc<0><<<g1, 512, 0, stream>>>(xq, wq1, b1, s_a2, beta2, hq, nullptr, H, C);
  dim3 g2(M / 256, C / 256);  // 64 x 4
  gemm_bt_dc<1><<<g2, 512, 0, stream>>>(hq, wq2, b2, nullptr, nullptr, nullptr, out, C, H);
}